// Round 6
// baseline (176.299 us; speedup 1.0000x reference)
//
#include <hip/hip_runtime.h>

#define NN 100000
#define NE 3200000
#define FEAT 128
#define EMBED 128

typedef __attribute__((ext_vector_type(8))) __bf16 bf16x8;
typedef __attribute__((ext_vector_type(8))) unsigned short ushort8;
typedef __attribute__((ext_vector_type(4))) float f32x4;

static __device__ __forceinline__ unsigned short f2bf(float f) {
    unsigned u = __float_as_uint(f);
    return (unsigned short)((u + 0x7FFFu + ((u >> 16) & 1u)) >> 16);  // RNE
}

// ---------------------------------------------------------------------------
// w fp32 [128][128] -> bf16 bits (ushort) [128][128]
// ---------------------------------------------------------------------------
__global__ void convert_w(const float* __restrict__ w, unsigned short* __restrict__ wbf) {
    int i = blockIdx.x * 256 + threadIdx.x;
    if (i < EMBED * FEAT) wbf[i] = f2bf(w[i]);
}

// ---------------------------------------------------------------------------
// h_bf[n][e] = bf16( sum_f x[n][f] * w[e][f] ), via mfma_f32_16x16x32_bf16.
// (unchanged -- memory-bound, ~20 us)
// ---------------------------------------------------------------------------
__global__ __launch_bounds__(256)
void gemm_xwT(const float* __restrict__ x, const unsigned short* __restrict__ wbf,
              unsigned short* __restrict__ hbf) {
    int wave = blockIdx.x * 4 + (threadIdx.x >> 6);
    long row0 = (long)wave * 16;
    if (row0 >= NN) return;
    int lane = threadIdx.x & 63;
    int r = lane & 15, kg = lane >> 4;

    const float4* x4 = (const float4*)x;  // [row*32 + fc4]
    const bf16x8* wb = (const bf16x8*)wbf;

    bf16x8 afr[4];
#pragma unroll
    for (int ks = 0; ks < 4; ++ks) {
        long base = (row0 + r) * 32 + ks * 8 + kg * 2;
        float4 v0 = x4[base];
        float4 v1 = x4[base + 1];
        float xf[8] = {v0.x, v0.y, v0.z, v0.w, v1.x, v1.y, v1.z, v1.w};
        ushort8 au;
#pragma unroll
        for (int e = 0; e < 8; ++e) au[e] = f2bf(xf[e]);
        afr[ks] = __builtin_bit_cast(bf16x8, au);
    }

    f32x4 acc[8];
#pragma unroll
    for (int nt = 0; nt < 8; ++nt) acc[nt] = (f32x4){0.f, 0.f, 0.f, 0.f};

#pragma unroll
    for (int nt = 0; nt < 8; ++nt) {
#pragma unroll
        for (int ks = 0; ks < 4; ++ks) {
            bf16x8 b = wb[(nt * 16 + r) * 16 + ks * 4 + kg];
            acc[nt] = __builtin_amdgcn_mfma_f32_16x16x32_bf16(afr[ks], b, acc[nt], 0, 0, 0);
        }
    }

#pragma unroll
    for (int nt = 0; nt < 8; ++nt) {
#pragma unroll
        for (int reg = 0; reg < 4; ++reg) {
            hbf[(row0 + kg * 4 + reg) * 128 + nt * 16 + r] = f2bf(acc[nt][reg]);
        }
    }
}

// ---------------------------------------------------------------------------
// CSR row offsets from sorted edge_dst via per-node lower_bound.
// ---------------------------------------------------------------------------
__global__ void build_rowptr(const int* __restrict__ dst, int* __restrict__ rowptr) {
    int n = blockIdx.x * blockDim.x + threadIdx.x;
    if (n > NN) return;
    int lo = 0, hi = NE;
    while (lo < hi) {
        int mid = (lo + hi) >> 1;
        if (dst[mid] < n) lo = mid + 1; else hi = mid;
    }
    rowptr[n] = lo;
}

// ---------------------------------------------------------------------------
// 8 consecutive dst nodes per wave (dst-sorted -> contiguous edge ranges;
// amortizes wave launch, rowptr latency, reduction drain 8x, and node k+1's
// scalar meta loads + gathers overlap node k's reduction/store).
// Per node: R4 structure -- 4 edges/iter, lane = (edge slot q=l>>4, col-quad
// c=l&15), one global_load_dwordx4 = 4 full bf16 h-rows = 1 KB/wave/instr.
// Metadata via wave-uniform scalar loads (s_load_dwordx4). Clamp-free bulk
// loop + single predicated tail per node. Static acc indexing throughout.
// Combine: 2 shfl_xor rounds per node; q==0 lanes store (each out row
// written exactly once -- covers poisoned d_out).
// ---------------------------------------------------------------------------
#define CONS(vj, wjv)                                                         \
    acc[0] += wjv * __uint_as_float(vj.x << 16);                              \
    acc[1] += wjv * __uint_as_float(vj.x & 0xFFFF0000u);                      \
    acc[2] += wjv * __uint_as_float(vj.y << 16);                              \
    acc[3] += wjv * __uint_as_float(vj.y & 0xFFFF0000u);                      \
    acc[4] += wjv * __uint_as_float(vj.z << 16);                              \
    acc[5] += wjv * __uint_as_float(vj.z & 0xFFFF0000u);                      \
    acc[6] += wjv * __uint_as_float(vj.w << 16);                              \
    acc[7] += wjv * __uint_as_float(vj.w & 0xFFFF0000u);

__global__ __launch_bounds__(256)
void aggregate(const unsigned int* __restrict__ h32, const float* __restrict__ ew,
               const int* __restrict__ src, const int* __restrict__ rowptr,
               float* __restrict__ out) {
    int wave = (int)((blockIdx.x * 256u + threadIdx.x) >> 6);
    int lane = threadIdx.x & 63;
    int nid0 = wave * 8;
    if (nid0 >= NN) return;

    int q = lane >> 4;
    int c = lane & 15;
    const uint4* h4 = (const uint4*)h32;  // [row*16 + c]

    int start = __builtin_amdgcn_readfirstlane(rowptr[nid0]);
    int nmax = NN - nid0 < 8 ? NN - nid0 : 8;

    for (int k = 0; k < nmax; ++k) {
        int nid = nid0 + k;
        int end = __builtin_amdgcn_readfirstlane(rowptr[nid + 1]);

        float acc[8];
#pragma unroll
        for (int j = 0; j < 8; ++j) acc[j] = 0.f;

        int i = start;
        int nfull = (end - start) >> 2;
#pragma unroll 4
        for (int b = 0; b < nfull; ++b, i += 4) {
            int s0 = src[i], s1 = src[i + 1], s2 = src[i + 2], s3 = src[i + 3];
            float w0 = ew[i], w1 = ew[i + 1], w2 = ew[i + 2], w3 = ew[i + 3];
            int   si = q == 0 ? s0 : (q == 1 ? s1 : (q == 2 ? s2 : s3));
            float wi = q == 0 ? w0 : (q == 1 ? w1 : (q == 2 ? w2 : w3));
            uint4 v = h4[(unsigned)si * 16u + (unsigned)c];
            CONS(v, wi)
        }
        if (i < end) {  // tail: clamp index, zero weight for OOB slots
            int last = end - 1;
            int i1 = i + 1 < end ? i + 1 : last;
            int i2 = i + 2 < end ? i + 2 : last;
            int s0 = src[i], s1 = src[i1], s2 = src[i2];
            float w0 = ew[i];
            float w1 = i + 1 < end ? ew[i1] : 0.f;
            float w2 = i + 2 < end ? ew[i2] : 0.f;
            int   si = q == 0 ? s0 : (q == 1 ? s1 : s2);
            float wi = q == 0 ? w0 : (q == 1 ? w1 : (q == 2 ? w2 : 0.f));
            uint4 v = h4[(unsigned)si * 16u + (unsigned)c];
            CONS(v, wi)
        }
        start = end;  // contiguous ranges: next node's start = this end

        // combine edge slots: lanes {l, l^16, l^32, l^48} share the same cols
#pragma unroll
        for (int j = 0; j < 8; ++j) {
            acc[j] += __shfl_xor(acc[j], 16);
            acc[j] += __shfl_xor(acc[j], 32);
        }

        if (q == 0) {
            float4* op = (float4*)(out + (long)nid * 128 + c * 8);
            op[0] = make_float4(acc[0], acc[1], acc[2], acc[3]);
            op[1] = make_float4(acc[4], acc[5], acc[6], acc[7]);
        }
    }
}

extern "C" void kernel_launch(void* const* d_in, const int* in_sizes, int n_in,
                              void* d_out, int out_size, void* d_ws, size_t ws_size,
                              hipStream_t stream) {
    const float* x    = (const float*)d_in[0];
    const float* w    = (const float*)d_in[1];
    const float* ew   = (const float*)d_in[2];
    const int*   esrc = (const int*)d_in[3];
    const int*   edst = (const int*)d_in[4];
    float* out = (float*)d_out;

    unsigned short* hbf = (unsigned short*)d_ws;                       // 25.6 MB
    int* rowptr = (int*)((char*)d_ws + (size_t)NN * 128 * 2);          // +400 KB
    unsigned short* wbf = (unsigned short*)((char*)d_ws + (size_t)NN * 128 * 2 + 400016);

    convert_w<<<64, 256, 0, stream>>>(w, wbf);
    gemm_xwT<<<(NN / 16 + 3) / 4, 256, 0, stream>>>(x, wbf, hbf);
    build_rowptr<<<(NN + 1 + 255) / 256, 256, 0, stream>>>(edst, rowptr);
    // 8 nodes/wave, 4 waves/block -> 32 nodes/block
    aggregate<<<(NN + 31) / 32, 256, 0, stream>>>((const unsigned int*)hbf, ew, esrc, rowptr, out);
}